// Round 15
// baseline (86.748 us; speedup 1.0000x reference)
//
#include <hip/hip_runtime.h>

// Problem constants: B=2, N=2048, F_IN=128, H=8, F=32
constexpr int Bv  = 2;
constexpr int Nv  = 2048;
constexpr int FIN = 128;
constexpr int Hn  = 8;
constexpr int Fv  = 32;
constexpr int NROW = Bv * Nv;      // 4096 rows
constexpr int S    = NROW * Hn;    // 32768 floats per PQ array

typedef float v4f __attribute__((ext_vector_type(4)));

// ---------------------------------------------------------------------------
// prep v2 (unchanged, measured-good): 256 blocks x 16 rows; wa + x in LDS;
// (row,h) split across 2 lanes, shfl_xor combine; writes Pj,Qj,Pi,Qi.
// ---------------------------------------------------------------------------
constexpr int PREP_RPB = 16;

__global__ __launch_bounds__(256) void prep_kernel(
    const float* __restrict__ w, const float* __restrict__ a,
    const float* __restrict__ x, float* __restrict__ pq) {
    __shared__ float wa[2 * FIN * Hn];     // 8 KB
    __shared__ float xs[PREP_RPB][FIN];    // 8 KB
    const int tid  = threadIdx.x;
    const int row0 = blockIdx.x * PREP_RPB;

    for (int e = tid; e < 2 * FIN * Hn; e += 256) {
        const int which = e >> 10;
        const int k     = (e >> 3) & (FIN - 1);
        const int h     = e & (Hn - 1);
        const float* ap = a + which * Fv;
        const float* wp = w + (size_t)k * (Fv * Hn) + h * Fv;
        float s = 0.f;
        #pragma unroll
        for (int f = 0; f < Fv; ++f) s = fmaf(wp[f], ap[f], s);
        wa[e] = s;
    }
    {
        float4* xs4 = (float4*)&xs[0][0];
        const float4* xg = (const float4*)(x + (size_t)row0 * FIN);
        #pragma unroll
        for (int i = tid; i < PREP_RPB * FIN / 4; i += 256) xs4[i] = xg[i];
    }
    __syncthreads();

    const int r    = tid >> 4;
    const int rem  = tid & 15;
    const int h    = rem >> 1;
    const int half = rem & 1;
    const int k0   = half * 64;

    float sj = 0.f, si = 0.f;
    #pragma unroll 8
    for (int k = 0; k < 64; ++k) {
        const int kk = k0 + k;
        const float xv = xs[r][kk];
        sj = fmaf(xv, wa[kk * Hn + h], sj);
        si = fmaf(xv, wa[FIN * Hn + kk * Hn + h], si);
    }
    sj += __shfl_xor(sj, 1);
    si += __shfl_xor(si, 1);

    if (half == 0) {
        const int row = row0 + r;
        const int idx = row * Hn + h;
        pq[idx]         = __expf(sj);
        pq[S + idx]     = __expf(0.2f * sj);
        pq[2 * S + idx] = __expf(si);
        pq[3 * S + idx] = __expf(0.2f * si);
    }
}

// ---------------------------------------------------------------------------
// fused row kernel: ONE WAVE = ONE ROW. No LDS, no barriers, 4 independent
// waves per block, 1024 blocks.
//   N-phase: prefetch g row (8 x v4f/lane, nt, read-once); g is exactly
//            {0,1}: predicated accumulate acc[h] += max(pi*Pj, qi*Qj) only
//            where g!=0 (inactive lanes fetch nothing -> ~20x less L2).
//   reduce:  8 accs x shfl_xor butterfly (all lanes get totals).
//   S-phase: stream the 64 KB row: slot s = it*64+lane, j=s>>1, head-half
//            = s&1 = lane&1 (loop-invariant); 1 KB contiguous per wave-store.
// ---------------------------------------------------------------------------
__global__ __launch_bounds__(256) void row_kernel(
    const float* __restrict__ g, const float* __restrict__ pq,
    float* __restrict__ out) {
    const int wv   = threadIdx.x >> 6;
    const int lane = threadIdx.x & 63;
    const int row  = blockIdx.x * 4 + wv;
    const int b    = row >> 11;

    const v4f*    __restrict__ g4  = (const v4f*)(g + (size_t)row * Nv);
    const float4* __restrict__ Pj4 = (const float4*)(pq + (size_t)b * Nv * Hn);
    const float4* __restrict__ Qj4 = (const float4*)(pq + S + (size_t)b * Nv * Hn);

    // prefetch entire g row: 8 independent nt loads in flight
    v4f gv[8];
    #pragma unroll
    for (int it = 0; it < 8; ++it)
        gv[it] = __builtin_nontemporal_load(&g4[it * 64 + lane]);

    float pi[Hn], qi[Hn];
    #pragma unroll
    for (int h = 0; h < Hn; ++h) {
        pi[h] = pq[2 * S + row * Hn + h];
        qi[h] = pq[3 * S + row * Hn + h];
    }

    float acc[Hn];
    #pragma unroll
    for (int h = 0; h < Hn; ++h) acc[h] = 0.f;

#define ACCJ(jj)                                                         \
    {                                                                    \
        const int _j = (jj);                                             \
        const float4 p0 = Pj4[2 * _j], p1 = Pj4[2 * _j + 1];             \
        const float4 q0 = Qj4[2 * _j], q1 = Qj4[2 * _j + 1];             \
        acc[0] += fmaxf(pi[0] * p0.x, qi[0] * q0.x);                     \
        acc[1] += fmaxf(pi[1] * p0.y, qi[1] * q0.y);                     \
        acc[2] += fmaxf(pi[2] * p0.z, qi[2] * q0.z);                     \
        acc[3] += fmaxf(pi[3] * p0.w, qi[3] * q0.w);                     \
        acc[4] += fmaxf(pi[4] * p1.x, qi[4] * q1.x);                     \
        acc[5] += fmaxf(pi[5] * p1.y, qi[5] * q1.y);                     \
        acc[6] += fmaxf(pi[6] * p1.z, qi[6] * q1.z);                     \
        acc[7] += fmaxf(pi[7] * p1.w, qi[7] * q1.w);                     \
    }

    // sparse predicated accumulate (g in {0,1}: no multiply needed)
    #pragma unroll
    for (int it = 0; it < 8; ++it) {
        const int j0 = (it * 64 + lane) * 4;
        if (gv[it].x != 0.f) ACCJ(j0)
        if (gv[it].y != 0.f) ACCJ(j0 + 1)
        if (gv[it].z != 0.f) ACCJ(j0 + 2)
        if (gv[it].w != 0.f) ACCJ(j0 + 3)
    }
#undef ACCJ

    // wave butterfly reduce: every lane ends with the row totals
    #pragma unroll
    for (int h = 0; h < Hn; ++h) {
        float v = acc[h];
        #pragma unroll
        for (int off = 32; off > 0; off >>= 1) v += __shfl_xor(v, off);
        acc[h] = v;
    }

    // per-lane head-half fold of 1/norm (static indices, cndmask selects)
    const bool odd = (lane & 1) != 0;
    float prv[4], qrv[4];
    #pragma unroll
    for (int c = 0; c < 4; ++c) {
        const float ns = odd ? acc[4 + c] : acc[c];
        const float pv = odd ? pi[4 + c] : pi[c];
        const float qv = odd ? qi[4 + c] : qi[c];
        const float rn = 1.0f / ns;          // norm > 0 (diag of g)
        prv[c] = pv * rn;
        qrv[c] = qv * rn;
    }

    // stream-store the row
    float4* __restrict__ orow = (float4*)(out + (size_t)row * Nv * Hn);
    #pragma unroll 8
    for (int it = 0; it < 64; ++it) {
        const int s = it * 64 + lane;
        const float4 pj = Pj4[s];
        const float4 qj = Qj4[s];
        float4 o;
        o.x = fmaxf(prv[0] * pj.x, qrv[0] * qj.x);
        o.y = fmaxf(prv[1] * pj.y, qrv[1] * qj.y);
        o.z = fmaxf(prv[2] * pj.z, qrv[2] * qj.z);
        o.w = fmaxf(prv[3] * pj.w, qrv[3] * qj.w);
        orow[s] = o;
    }
}

// ---------------------------------------------------------------------------
extern "C" void kernel_launch(void* const* d_in, const int* in_sizes, int n_in,
                              void* d_out, int out_size, void* d_ws, size_t ws_size,
                              hipStream_t stream) {
    const float* g = (const float*)d_in[0];   // (B,N,N)
    const float* x = (const float*)d_in[1];   // (B,N,F_IN)
    const float* w = (const float*)d_in[2];   // (F_IN, F*H)
    const float* a = (const float*)d_in[3];   // (2F,)

    float* pq  = (float*)d_ws;                // 4*S floats = 512 KB
    float* out = (float*)d_out;               // (B,N,N,H) fp32

    prep_kernel<<<NROW / PREP_RPB, 256, 0, stream>>>(w, a, x, pq);
    row_kernel<<<NROW / 4, 256, 0, stream>>>(g, pq, out);
}

// Round 18
// 80.877 us; speedup vs baseline: 1.0726x; 1.0726x over previous
//
#include <hip/hip_runtime.h>

// Problem constants: B=2, N=2048, F_IN=128, H=8, F=32
constexpr int Bv  = 2;
constexpr int Nv  = 2048;
constexpr int FIN = 128;
constexpr int Hn  = 8;
constexpr int Fv  = 32;
constexpr int NROW = Bv * Nv;      // 4096 rows
constexpr int S    = NROW * Hn;    // 32768 floats per PQ array

// ---------------------------------------------------------------------------
// prep v2 (r13 verbatim): 256 blocks x 16 rows; wa + x in LDS; (row,h) split
// across 2 lanes, shfl_xor combine; writes Pj,Qj,Pi,Qi.
// ---------------------------------------------------------------------------
constexpr int PREP_RPB = 16;

__global__ __launch_bounds__(256) void prep_kernel(
    const float* __restrict__ w, const float* __restrict__ a,
    const float* __restrict__ x, float* __restrict__ pq) {
    __shared__ float wa[2 * FIN * Hn];     // 8 KB
    __shared__ float xs[PREP_RPB][FIN];    // 8 KB
    const int tid  = threadIdx.x;
    const int row0 = blockIdx.x * PREP_RPB;

    for (int e = tid; e < 2 * FIN * Hn; e += 256) {
        const int which = e >> 10;
        const int k     = (e >> 3) & (FIN - 1);
        const int h     = e & (Hn - 1);
        const float* ap = a + which * Fv;
        const float* wp = w + (size_t)k * (Fv * Hn) + h * Fv;
        float s = 0.f;
        #pragma unroll
        for (int f = 0; f < Fv; ++f) s = fmaf(wp[f], ap[f], s);
        wa[e] = s;
    }
    {
        float4* xs4 = (float4*)&xs[0][0];
        const float4* xg = (const float4*)(x + (size_t)row0 * FIN);
        #pragma unroll
        for (int i = tid; i < PREP_RPB * FIN / 4; i += 256) xs4[i] = xg[i];
    }
    __syncthreads();

    const int r    = tid >> 4;
    const int rem  = tid & 15;
    const int h    = rem >> 1;
    const int half = rem & 1;
    const int k0   = half * 64;

    float sj = 0.f, si = 0.f;
    #pragma unroll 8
    for (int k = 0; k < 64; ++k) {
        const int kk = k0 + k;
        const float xv = xs[r][kk];
        sj = fmaf(xv, wa[kk * Hn + h], sj);
        si = fmaf(xv, wa[FIN * Hn + kk * Hn + h], si);
    }
    sj += __shfl_xor(sj, 1);
    si += __shfl_xor(si, 1);

    if (half == 0) {
        const int row = row0 + r;
        const int idx = row * Hn + h;
        pq[idx]         = __expf(sj);
        pq[S + idx]     = __expf(0.2f * sj);
        pq[2 * S + idx] = __expf(si);
        pq[3 * S + idx] = __expf(0.2f * si);
    }
}

// ---------------------------------------------------------------------------
// norm v2 (r13 verbatim): one block per row; 2 x float4 g loads up front,
// 4 ballots/iter cross-wave compaction (ascending j), gather-accumulate,
// reduce, write tbl[row] = {pi*rn, qi*rn}.
// ---------------------------------------------------------------------------
__global__ __launch_bounds__(256) void norm_kernel(
    const float* __restrict__ g, const float* __restrict__ pq,
    float* __restrict__ tbl) {
    const int row  = blockIdx.x;
    const int b    = row >> 11;
    const int tid  = threadIdx.x;
    const int lane = tid & 63, wv = tid >> 6;

    __shared__ int   idxs[Nv];       // 8 KB
    __shared__ int   wavesum[4];
    __shared__ int   base_s;
    __shared__ float red[4][Hn];

    if (tid == 0) base_s = 0;

    const float4* __restrict__ g4 = (const float4*)(g + (size_t)row * Nv);
    const float4 gva = g4[tid];
    const float4 gvb = g4[tid + 256];

    float pi[Hn], qi[Hn];
    #pragma unroll
    for (int h = 0; h < Hn; ++h) {
        pi[h] = pq[2 * S + row * Hn + h];
        qi[h] = pq[3 * S + row * Hn + h];
    }

    const unsigned long long below = (1ull << lane) - 1ull;

    {
        const float4 gv = gva;
        const int j0 = 4 * tid;
        const unsigned long long m0 = __ballot(gv.x != 0.f);
        const unsigned long long m1 = __ballot(gv.y != 0.f);
        const unsigned long long m2 = __ballot(gv.z != 0.f);
        const unsigned long long m3 = __ballot(gv.w != 0.f);
        if (lane == 0)
            wavesum[wv] = __popcll(m0) + __popcll(m1) + __popcll(m2) + __popcll(m3);
        __syncthreads();
        int off = base_s;
        #pragma unroll
        for (int w2 = 0; w2 < 4; ++w2) if (w2 < wv) off += wavesum[w2];
        const int total = wavesum[0] + wavesum[1] + wavesum[2] + wavesum[3];
        off += __popcll(m0 & below) + __popcll(m1 & below)
             + __popcll(m2 & below) + __popcll(m3 & below);
        if (gv.x != 0.f) idxs[off++] = j0;
        if (gv.y != 0.f) idxs[off++] = j0 + 1;
        if (gv.z != 0.f) idxs[off++] = j0 + 2;
        if (gv.w != 0.f) idxs[off++] = j0 + 3;
        __syncthreads();
        if (tid == 0) base_s += total;
    }
    {
        const float4 gv = gvb;
        const int j0 = 1024 + 4 * tid;
        const unsigned long long m0 = __ballot(gv.x != 0.f);
        const unsigned long long m1 = __ballot(gv.y != 0.f);
        const unsigned long long m2 = __ballot(gv.z != 0.f);
        const unsigned long long m3 = __ballot(gv.w != 0.f);
        if (lane == 0)
            wavesum[wv] = __popcll(m0) + __popcll(m1) + __popcll(m2) + __popcll(m3);
        __syncthreads();
        int off = base_s;
        #pragma unroll
        for (int w2 = 0; w2 < 4; ++w2) if (w2 < wv) off += wavesum[w2];
        const int total = wavesum[0] + wavesum[1] + wavesum[2] + wavesum[3];
        off += __popcll(m0 & below) + __popcll(m1 & below)
             + __popcll(m2 & below) + __popcll(m3 & below);
        if (gv.x != 0.f) idxs[off++] = j0;
        if (gv.y != 0.f) idxs[off++] = j0 + 1;
        if (gv.z != 0.f) idxs[off++] = j0 + 2;
        if (gv.w != 0.f) idxs[off++] = j0 + 3;
        __syncthreads();
        if (tid == 0) base_s += total;
    }
    __syncthreads();
    const int cnt = base_s;

    const float4* __restrict__ Pj4 = (const float4*)(pq + (size_t)b * Nv * Hn);
    const float4* __restrict__ Qj4 = (const float4*)(pq + S + (size_t)b * Nv * Hn);

    float acc[Hn];
    #pragma unroll
    for (int h = 0; h < Hn; ++h) acc[h] = 0.f;

    for (int t = tid; t < cnt; t += 256) {
        const int jj = idxs[t];
        const float4 p0 = Pj4[2 * jj], p1 = Pj4[2 * jj + 1];
        const float4 q0 = Qj4[2 * jj], q1 = Qj4[2 * jj + 1];
        acc[0] += fmaxf(pi[0] * p0.x, qi[0] * q0.x);
        acc[1] += fmaxf(pi[1] * p0.y, qi[1] * q0.y);
        acc[2] += fmaxf(pi[2] * p0.z, qi[2] * q0.z);
        acc[3] += fmaxf(pi[3] * p0.w, qi[3] * q0.w);
        acc[4] += fmaxf(pi[4] * p1.x, qi[4] * q1.x);
        acc[5] += fmaxf(pi[5] * p1.y, qi[5] * q1.y);
        acc[6] += fmaxf(pi[6] * p1.z, qi[6] * q1.z);
        acc[7] += fmaxf(pi[7] * p1.w, qi[7] * q1.w);
    }

    #pragma unroll
    for (int h = 0; h < Hn; ++h) {
        float v = acc[h];
        #pragma unroll
        for (int off = 32; off > 0; off >>= 1) v += __shfl_down(v, off);
        if (lane == 0) red[wv][h] = v;
    }
    __syncthreads();
    if (tid < Hn) {
        const float nsum = red[0][tid] + red[1][tid] + red[2][tid] + red[3][tid];
        const float rn = 1.0f / nsum;          // diag guarantees nsum > 0
        const float piv = pq[2 * S + row * Hn + tid];
        const float qiv = pq[3 * S + row * Hn + tid];
        tbl[row * 16 + tid]     = piv * rn;
        tbl[row * 16 + 8 + tid] = qiv * rn;
    }
}

// ---------------------------------------------------------------------------
// out v5: MEMSET-SWEEP pattern (fill-mimic A/B). Global thread gtid owns the
// FIXED float4 slot s = gtid & 4095 of rows {it*128 + (gtid>>12)}, it=0..31.
// idx4 = it*524288 + gtid: at any instant all 524288 threads write one
// contiguous sweeping window — exactly the fill's store-address footprint.
// Pj/Qj register-cached per batch-half; 2 wave-uniform tbl loads + 12 VALU
// + 1 store per iteration.
// ---------------------------------------------------------------------------
__global__ __launch_bounds__(256) void out_kernel(
    const float* __restrict__ pq, const float* __restrict__ tbl,
    float* __restrict__ out) {
    const int gtid = blockIdx.x * 256 + threadIdx.x;   // 0..524287
    const int s    = gtid & 4095;      // fixed float4 slot within every row
    const int hh   = s & 1;            // head-half (slot parity)

    float4* __restrict__ out4 = (float4*)out;

    // ---- batch 0: it = 0..15 ----
    {
        const float4* __restrict__ Pb = (const float4*)pq;
        const float4* __restrict__ Qb = (const float4*)(pq + S);
        const float4 pj = Pb[s];
        const float4 qj = Qb[s];
        #pragma unroll 4
        for (int it = 0; it < 16; ++it) {
            const size_t idx4 = (size_t)it * 524288 + gtid;
            const int row = (int)(idx4 >> 12);
            const float4 prv = *(const float4*)(tbl + row * 16 + hh * 4);
            const float4 qrv = *(const float4*)(tbl + row * 16 + 8 + hh * 4);
            float4 o;
            o.x = fmaxf(prv.x * pj.x, qrv.x * qj.x);
            o.y = fmaxf(prv.y * pj.y, qrv.y * qj.y);
            o.z = fmaxf(prv.z * pj.z, qrv.z * qj.z);
            o.w = fmaxf(prv.w * pj.w, qrv.w * qj.w);
            out4[idx4] = o;
        }
    }
    // ---- batch 1: it = 16..31 ----
    {
        const float4* __restrict__ Pb = (const float4*)(pq + (size_t)Nv * Hn);
        const float4* __restrict__ Qb = (const float4*)(pq + S + (size_t)Nv * Hn);
        const float4 pj = Pb[s];
        const float4 qj = Qb[s];
        #pragma unroll 4
        for (int it = 16; it < 32; ++it) {
            const size_t idx4 = (size_t)it * 524288 + gtid;
            const int row = (int)(idx4 >> 12);
            const float4 prv = *(const float4*)(tbl + row * 16 + hh * 4);
            const float4 qrv = *(const float4*)(tbl + row * 16 + 8 + hh * 4);
            float4 o;
            o.x = fmaxf(prv.x * pj.x, qrv.x * qj.x);
            o.y = fmaxf(prv.y * pj.y, qrv.y * qj.y);
            o.z = fmaxf(prv.z * pj.z, qrv.z * qj.z);
            o.w = fmaxf(prv.w * pj.w, qrv.w * qj.w);
            out4[idx4] = o;
        }
    }
}

// ---------------------------------------------------------------------------
extern "C" void kernel_launch(void* const* d_in, const int* in_sizes, int n_in,
                              void* d_out, int out_size, void* d_ws, size_t ws_size,
                              hipStream_t stream) {
    const float* g = (const float*)d_in[0];   // (B,N,N)
    const float* x = (const float*)d_in[1];   // (B,N,F_IN)
    const float* w = (const float*)d_in[2];   // (F_IN, F*H)
    const float* a = (const float*)d_in[3];   // (2F,)

    float* pq  = (float*)d_ws;                // 4*S floats = 512 KB
    float* tbl = pq + 4 * S;                  // 4096*16 floats = 256 KB
    float* out = (float*)d_out;               // (B,N,N,H) fp32

    prep_kernel<<<NROW / PREP_RPB, 256, 0, stream>>>(w, a, x, pq);
    norm_kernel<<<NROW, 256, 0, stream>>>(g, pq, tbl);
    out_kernel<<<2048, 256, 0, stream>>>(pq, tbl, out);
}